// Round 18
// baseline (4341.795 us; speedup 1.0000x reference)
//
#include <hip/hip_runtime.h>

#define DI __device__ __forceinline__

constexpr int B = 32, L = 100, T = 50;
constexpr int VS = 20000;
constexpr int HR = 250, HD = 500;
constexpr int INE = 460;
constexpr int OC = 1072;   // padded Wcat columns: 500 hwd | 60 hz | 500 hWo1 | 1 hwl | pad

// ---- workspace byte offsets ----
constexpr size_t O_X      = 0;                      // x [B][L][460] f32
constexpr size_t O_SX     = 5888000;                // sent_x [T][B][400] f32
constexpr size_t O_WIHFT  = 8448000;                // enc_Wih_f^T [460][1000] f32
constexpr size_t O_WIHBT  = 10288000;
constexpr size_t O_WDECT  = 12128000;               // dec_Wih^T [400][2000] f32
constexpr size_t O_W4ENC  = 15328000;               // transposed [2dir][250k][250u][4g] f32
constexpr size_t O_W4DEC  = 17328000;               // transposed [500k][500u][4g] f32
constexpr size_t O_WCAT   = 21328000;               // [500][1072] f32
constexpr size_t O_XWF    = 23472000;               // [100][32b][1000] f64  (b-major)
constexpr size_t O_XWB    = 49072000;
constexpr size_t O_XWD    = 74672000;               // [50][32b][2000] f64
constexpr size_t O_EOB    = 100272000;              // enc_out [32][100][500] f32
constexpr size_t O_E2     = 113072000;              // [32][100][500] f32
constexpr size_t O_PROJ   = 125872000;              // [50][32][1072] f32 (written AFTER dec)
// recurrence h-exchange buffers overlay the (later-written) PROJ region:
constexpr size_t O_EHB    = O_PROJ;                 // enc h [64ch][256] f64
constexpr size_t O_DHB    = O_PROJ + 131072;        // dec h [32ch][512] f64
constexpr size_t O_HD     = 139593600;              // [1600][500] f32 (row t*32+b)
constexpr size_t O_H0DEC  = 146249600;              // [500][32] f64 scrambled h init
constexpr size_t O_HENCF  = 146505600;              // [2dir][250][32] f64 final
constexpr size_t O_CENCF  = 146633600;
constexpr size_t O_CDEC0  = 146761600;              // [500][32] f64 scrambled c init
constexpr size_t O_HDECF  = 146889600;              // [500][32] f64 final
constexpr size_t O_CDECF  = 147017600;
constexpr size_t O_AD     = 147145600;              // a f32 [1600][100]
constexpr size_t O_ATTN   = 148425600;              // [32][50][100] f32
constexpr size_t O_EWL    = 149065600;              // [32][100] f32
constexpr size_t O_SXL    = 149091200;              // [1600] f32 (t*32+b)
constexpr size_t O_AWL    = 149104000;              // [1600] f32 (b*50+t)
constexpr size_t O_LAM    = 149116800;              // [1600] f32
constexpr size_t O_LS1    = 149123200;              // [1600] f32
constexpr size_t O_WIDX   = 149129600;              // [1600] int
constexpr size_t O_OUTS   = 149144192;              // outs f32 [1600][512]
constexpr size_t O_FLG    = 154090496;              // enc flags 8192 int | dec flags 8192 int
// end ~154.2 MB (<=158.4MB proven)

// output element offsets (f32)
constexpr size_t OUT_HT  = 32000000;
constexpr size_t OUT_CT  = 32016000;
constexpr size_t OUT_AP  = 32032000;
constexpr size_t OUT_DP  = 32512000;

DI double dsig(double x) { return 1.0 / (1.0 + exp(-x)); }
DI float fsig(float x) { return 1.f / (1.f + expf(-x)); }

// coherent (cache-bypassing, agent-scope) ops — the cross-block data path
DI double cld(const double* p) {
    return __hip_atomic_load(p, __ATOMIC_RELAXED, __HIP_MEMORY_SCOPE_AGENT);
}
DI void cst(double* p, double v) {
    __hip_atomic_store(p, v, __ATOMIC_RELAXED, __HIP_MEMORY_SCOPE_AGENT);
}
DI int cldi(const int* p) {
    return __hip_atomic_load(p, __ATOMIC_RELAXED, __HIP_MEMORY_SCOPE_AGENT);
}
DI void csti(int* p, int v) {
    __hip_atomic_store(p, v, __ATOMIC_RELAXED, __HIP_MEMORY_SCOPE_AGENT);
}
DI void spinge(const int* p, int target) {
    int spins = 0;
    while (cldi(p) < target) {
        __builtin_amdgcn_s_sleep(1);
        if (++spins > 50000000) break;     // bounded: no hang on bug
    }
}

// ---------------- prep kernels ----------------

__global__ void k_embed_x(const float* Es, const float* Ef, const float* Ep, const float* En,
                          const int* value, const int* field, const int* ppos, const int* pneg,
                          float* x) {
    int i = blockIdx.x * 256 + threadIdx.x;
    if (i >= B * L * INE) return;
    int j = i % INE, bl = i / INE;
    float v;
    if (j < 400)      v = Es[(size_t)value[bl] * 400 + j];
    else if (j < 450) v = Ef[(size_t)field[bl] * 50 + (j - 400)];
    else if (j < 455) v = Ep[(size_t)ppos[bl] * 5 + (j - 450)];
    else              v = En[(size_t)pneg[bl] * 5 + (j - 455)];
    x[i] = v;
}

__global__ void k_embed_sent(const float* Es, const int* sent, float* sx) {
    int i = blockIdx.x * 256 + threadIdx.x;
    if (i >= T * B * 400) return;
    int k = i % 400, tb = i / 400;
    int b = tb % B, t = tb / B;
    sx[i] = Es[(size_t)sent[b * T + t] * 400 + k];
}

__global__ void k_transpose(float* dst, const float* src, int K, int G) {
    int i = blockIdx.x * 256 + threadIdx.x;
    if (i >= K * G) return;
    int g = i % G, k = i / G;
    dst[i] = src[(size_t)g * K + k];
}

// transposed gate-pack: dst[(k*U + u)*4 + g] = src[(g*U+u)*Kh + k]
__global__ void k_pack4T(float* dst, const float* src, int U, int Kh) {
    int i = blockIdx.x * 256 + threadIdx.x;
    if (i >= U * Kh * 4) return;
    int g = i & 3, rest = i >> 2;
    int u = rest % U, k = rest / U;
    dst[i] = src[((size_t)(g * U + u)) * Kh + k];
}

__global__ void k_pack_wcat(float* dst, const float* Wd, const float* Wz, const float* Wo, const float* wl) {
    int i = blockIdx.x * 256 + threadIdx.x;
    if (i >= 500 * OC) return;
    int o = i % OC, d = i / OC;
    float v = 0.f;
    if (o < 500)       v = Wd[(size_t)d * 500 + o];
    else if (o < 560)  v = Wz[(size_t)d * 60 + (o - 500)];
    else if (o < 1060) v = Wo[(size_t)d * 500 + (o - 560)];
    else if (o == 1060) v = wl[d];
    dst[i] = v;
}

__global__ void k_zeroi(int* p, int n) {
    int i = blockIdx.x * 256 + threadIdx.x;
    if (i < n) p[i] = 0;
}

// out[t][b][g] = bias[g] + sum_k xs[b,t,k] * Wt[k][g]   (f64 accumulate — feeds the chaotic chain)
__global__ __launch_bounds__(256) void k_gemm_xw(double* out, const float* xs, int bstride, int tstride,
                                                 const float* Wt, const float* bias, int K, int G) {
    __shared__ float xls[460 * 33];
    int t = blockIdx.x;
    int g = blockIdx.y * 256 + threadIdx.x;
    bool act = g < G;
    for (int i = threadIdx.x; i < 32 * K; i += 256) {
        int b = i / K, k = i - b * K;
        xls[k * 33 + b] = xs[(size_t)b * bstride + (size_t)t * tstride + k];
    }
    __syncthreads();
    double acc[32];
    double bs = act ? (double)bias[g] : 0.0;
#pragma unroll
    for (int b = 0; b < 32; ++b) acc[b] = bs;
    for (int k = 0; k < K; ++k) {
        double w = act ? (double)Wt[(size_t)k * G + g] : 0.0;
        const float* xr = &xls[k * 33];
#pragma unroll
        for (int b = 0; b < 32; ++b) acc[b] += w * (double)xr[b];
    }
    if (act) {
#pragma unroll
        for (int b = 0; b < 32; ++b)
            out[((size_t)t * 32 + b) * G + g] = acc[b];
    }
}

// ---------------- encoder: 256 blocks = 64 chains x 4 u-quarters, register W-cache ----------------

__global__ __launch_bounds__(1024) void k_enc_u(const double* xw2F, const double* xw2B,
                                                const float* w4T, double* HB, int* FLG,
                                                float* eoB, double* hencF, double* cencF) {
    __shared__ double h_s[256];
    __shared__ double pz[15][4][64];          // kc 1..15 partials, [gate][ul] conflict-free
    int gid = blockIdx.x;
    int chain = gid >> 2, q = gid & 3;
    int dir = chain >> 5, b = chain & 31;
    int tid = threadIdx.x;
    int kc = tid >> 6, ul = tid & 63;
    int u0 = (q * 250) >> 2, u1 = ((q + 1) * 250) >> 2;
    int nu = u1 - u0;                          // 62 or 63
    int u = u0 + ul;
    bool act = ul < nu;
    int usafe = act ? u : u0;
    int ks = (kc * 250) >> 4, ke = ((kc + 1) * 250) >> 4;
    int ntrip = ke - ks;                       // 15 or 16
    const double* xw = dir ? xw2B : xw2F;
    const float4* W = (const float4*)w4T + (size_t)dir * 250 * 250;   // [k][u]
    double* myHB = HB + (size_t)chain * 256;
    int* flg = FLG + chain * 64;               // 4 slots x 16 ints
    double c = 0.0;
    // W is step-invariant: cache this thread's slice in registers ONCE
    float4 wreg[16];
#pragma unroll
    for (int j = 0; j < 16; ++j) {
        int k = ks + j;
        wreg[j] = (j < ntrip) ? W[(size_t)k * 250 + usafe]
                              : make_float4(0.f, 0.f, 0.f, 0.f);
    }
    if (tid < 256) h_s[tid] = 0.0;
    __syncthreads();
    for (int s = 0; s < L; ++s) {
        int tin = dir ? (L - 1 - s) : s;
        double zi = 0.0, zf = 0.0, zg = 0.0, zo = 0.0;
        if (act) {
#pragma unroll
            for (int j = 0; j < 16; ++j) {
                double hv = h_s[ks + j];       // idx <= 250 < 256; pad lanes hit zeroed LDS
                float4 w = wreg[j];
                zi += (double)w.x * hv; zf += (double)w.y * hv;
                zg += (double)w.z * hv; zo += (double)w.w * hv;
            }
            if (kc) { pz[kc - 1][0][ul] = zi; pz[kc - 1][1][ul] = zf;
                      pz[kc - 1][2][ul] = zg; pz[kc - 1][3][ul] = zo; }
        }
        __syncthreads();
        if (act && kc == 0) {
            const double* x0 = xw + ((size_t)tin * 32 + b) * 1000;
            double Zi = x0[0 * HR + u] + zi, Zf = x0[1 * HR + u] + zf;
            double Zg = x0[2 * HR + u] + zg, Zo = x0[3 * HR + u] + zo;
#pragma unroll
            for (int j = 0; j < 15; ++j) {
                Zi += pz[j][0][ul]; Zf += pz[j][1][ul];
                Zg += pz[j][2][ul]; Zo += pz[j][3][ul];
            }
            double cn = dsig(Zf) * c + dsig(Zi) * tanh(Zg);
            double hn = dsig(Zo) * tanh(cn);
            c = cn;
            cst(&myHB[u], hn);
            eoB[((size_t)b * 100 + tin) * 500 + dir * 250 + u] = (float)hn;
            if (s == L - 1) {
                hencF[dir * 8000 + u * 32 + b] = hn;
                cencF[dir * 8000 + u * 32 + b] = cn;
            }
        }
        __syncthreads();                      // drain coherent h stores (release)
        if (tid == 0) csti(&flg[q * 16], s + 1);
        if (tid < 4) spinge(&flg[tid * 16], s + 1);
        __syncthreads();
        if (tid < 250) h_s[tid] = cld(&myHB[tid]);
        __syncthreads();
    }
}

// replicate torch .view on [2,B,250] -> [B,500]
__global__ void k_scramble(double* h0dec, double* cdec0, const double* hencF, const double* cencF) {
    int gt = blockIdx.x * 256 + threadIdx.x;
    if (gt >= 16000) return;
    int bb = gt / 500, j = gt - bb * 500;
    int d = gt / 8000, rem = gt - d * 8000;
    int bs = rem / 250, us = rem - bs * 250;
    h0dec[j * 32 + bb] = hencF[d * 8000 + us * 32 + bs];
    cdec0[j * 32 + bb] = cencF[d * 8000 + us * 32 + bs];
}

// ---------------- decoder: 256 blocks = 32 chains x 8 u-eighths, partial register W-cache ----------------

__global__ __launch_bounds__(1024) void k_dec_u(const double* h0dec, const double* cdec0,
                                                const double* xw2D, const float* w4T,
                                                double* HB, int* FLG,
                                                float* Hd, double* hdecF, double* cdecF) {
    __shared__ double h_s[512];
    __shared__ double pz[15][4][64];
    int gid = blockIdx.x;
    int chain = gid >> 3, q = gid & 7;
    int b = chain;
    int tid = threadIdx.x;
    int kc = tid >> 6, ul = tid & 63;
    int u0 = (q * 500) >> 3, u1 = ((q + 1) * 500) >> 3;
    int nu = u1 - u0;                          // 62 or 63
    int u = u0 + ul;
    bool act = ul < nu;
    int usafe = act ? u : u0;
    int ks = (kc * 500) >> 4, ke = ((kc + 1) * 500) >> 4;   // 31 or 32 trips
    const float4* W = (const float4*)w4T;      // [k][u]
    double* myHB = HB + (size_t)chain * 512;
    int* flg = FLG + chain * 128;              // 8 slots x 16 ints
    double c = (act && kc == 0) ? cdec0[u * 32 + b] : 0.0;
    // cache first 16 k-trips in registers (step-invariant); stream the tail
    float4 wreg[16];
#pragma unroll
    for (int j = 0; j < 16; ++j)
        wreg[j] = W[(size_t)(ks + j) * 500 + usafe];   // ntrip >= 31 > 16 always
    if (tid < 512) h_s[tid] = (tid < 500) ? h0dec[tid * 32 + b] : 0.0;
    __syncthreads();
    for (int t = 0; t < T; ++t) {
        double zi = 0.0, zf = 0.0, zg = 0.0, zo = 0.0;
        if (act) {
#pragma unroll
            for (int j = 0; j < 16; ++j) {
                double hv = h_s[ks + j];
                float4 w = wreg[j];
                zi += (double)w.x * hv; zf += (double)w.y * hv;
                zg += (double)w.z * hv; zo += (double)w.w * hv;
            }
#pragma unroll 4
            for (int k = ks + 16; k < ke; ++k) {
                float4 w = W[(size_t)k * 500 + u];   // streamed tail, L2-resident
                double hv = h_s[k];
                zi += (double)w.x * hv; zf += (double)w.y * hv;
                zg += (double)w.z * hv; zo += (double)w.w * hv;
            }
            if (kc) { pz[kc - 1][0][ul] = zi; pz[kc - 1][1][ul] = zf;
                      pz[kc - 1][2][ul] = zg; pz[kc - 1][3][ul] = zo; }
        }
        __syncthreads();
        if (act && kc == 0) {
            const double* x0 = xw2D + ((size_t)t * 32 + b) * 2000;
            double Zi = x0[0 * HD + u] + zi, Zf = x0[1 * HD + u] + zf;
            double Zg = x0[2 * HD + u] + zg, Zo = x0[3 * HD + u] + zo;
#pragma unroll
            for (int j = 0; j < 15; ++j) {
                Zi += pz[j][0][ul]; Zf += pz[j][1][ul];
                Zg += pz[j][2][ul]; Zo += pz[j][3][ul];
            }
            double cn = dsig(Zf) * c + dsig(Zi) * tanh(Zg);
            double hn = dsig(Zo) * tanh(cn);
            c = cn;
            cst(&myHB[u], hn);
            Hd[((size_t)t * 32 + b) * 500 + u] = (float)hn;
            if (t == T - 1) {
                hdecF[u * 32 + b] = hn;
                cdecF[u * 32 + b] = cn;
            }
        }
        __syncthreads();                      // drain coherent h stores (release)
        if (tid == 0) csti(&flg[q * 16], t + 1);
        if (tid < 8) spinge(&flg[tid * 16], t + 1);
        __syncthreads();
        if (tid < 500) h_s[tid] = cld(&myHB[tid]);
        __syncthreads();
    }
}

// ---------------- attention precomputes (f32 — post-recurrence, bf16-graded outputs) ----------------

// E2[r][e] = sum_j eoB[r][j] * Wo[(500+j)][e] — 16-row tile x 256-col strip
__global__ __launch_bounds__(256) void k_e2_tiled(const float* eoB, const float* Wo, float* E2) {
    __shared__ float rows[8000];
    int et = blockIdx.x, mt = blockIdx.y;
    int tid = threadIdx.x;
    size_t rbase = (size_t)mt * 16 * 500;
    for (int i = tid; i < 8000; i += 256) rows[i] = eoB[rbase + i];
    __syncthreads();
    int e = et * 256 + tid;
    if (e >= 500) return;
    float acc[16];
#pragma unroll
    for (int m = 0; m < 16; ++m) acc[m] = 0.f;
    for (int d = 0; d < 500; ++d) {
        float w = Wo[(size_t)(500 + d) * 500 + e];
#pragma unroll
        for (int m = 0; m < 16; ++m) acc[m] += rows[m * 500 + d] * w;
    }
#pragma unroll
    for (int m = 0; m < 16; ++m) E2[rbase + (size_t)m * 500 + e] = acc[m];
}

__global__ void k_ewl(const float* eoB, const float* wl, float* E_wl) {
    int w = threadIdx.x >> 6, lane = threadIdx.x & 63;
    int r = blockIdx.x * 4 + w;
    if (r >= 3200) return;
    const float* eo = eoB + (size_t)r * 500;
    float p = 0.f;
    for (int j = lane; j < 500; j += 64) p += eo[j] * wl[500 + j];
    for (int off = 32; off > 0; off >>= 1) p += __shfl_down(p, off);
    if (lane == 0) E_wl[r] = p;
}

__global__ void k_sxl(const float* sx, const float* wl, float* SXL) {
    int i = blockIdx.x * 256 + threadIdx.x;
    if (i >= 1600) return;
    float acc = 0.f;
    for (int k = 0; k < 400; ++k) acc += sx[(size_t)i * 400 + k] * wl[1000 + k];
    SXL[i] = acc;
}

// PROJ[m2][o] = sum_d Hd[m2][d] * Wcat[d][o] — 16-row tile x 256-col strip
__global__ __launch_bounds__(256) void k_proj_tiled(const float* Hd, const float* Wcat, float* PROJ) {
    __shared__ float rows[8000];
    int ot = blockIdx.x, mt = blockIdx.y;
    int tid = threadIdx.x;
    size_t rbase = (size_t)mt * 16 * 500;
    for (int i = tid; i < 8000; i += 256) rows[i] = Hd[rbase + i];
    __syncthreads();
    int o = ot * 256 + tid;
    if (o >= OC) return;
    float acc[16];
#pragma unroll
    for (int m = 0; m < 16; ++m) acc[m] = 0.f;
    for (int d = 0; d < 500; ++d) {
        float w = Wcat[(size_t)d * OC + o];
#pragma unroll
        for (int m = 0; m < 16; ++m) acc[m] += rows[m * 500 + d] * w;
    }
#pragma unroll
    for (int m = 0; m < 16; ++m)
        PROJ[((size_t)(mt * 16 + m)) * OC + o] = acc[m];
}

// scores + dual softmax + attn/AD/widx/awl : one block per (t,b), f32
__global__ __launch_bounds__(256) void k_attn_all(
        const float* PROJ, const float* eoB, const float* x, const float* E_wl, const int* value,
        float* attn_ws, float* AD, float* AWL, int* widx) {
    int bid = blockIdx.x;              // = t*32+b
    int t = bid >> 5, b = bid & 31;
    int tid = threadIdx.x;
    int m = b * T + t;
    __shared__ float hwd_s[500], hz_s[60], sd_s[100], sz_s[100], aL[100];
    __shared__ float red[256];
    __shared__ int ri[256];
    const float* pr = PROJ + (size_t)bid * OC;
    for (int k = tid; k < 500; k += 256) hwd_s[k] = pr[k];
    if (tid < 60) hz_s[tid] = pr[500 + tid];
    __syncthreads();
    int w = tid >> 6, lane = tid & 63;
    for (int l = w; l < 100; l += 4) {
        const float* er = eoB + ((size_t)b * 100 + l) * 500;
        float p = 0.f;
        for (int e = lane; e < 500; e += 64) p += hwd_s[e] * er[e];
        for (int off = 32; off > 0; off >>= 1) p += __shfl_down(p, off);
        if (lane == 0) sd_s[l] = p;
        const float* zr = x + ((size_t)b * 100 + l) * 460 + 400;
        float qq = (lane < 60) ? hz_s[lane] * zr[lane] : 0.f;
        for (int off = 32; off > 0; off >>= 1) qq += __shfl_down(qq, off);
        if (lane == 0) sz_s[l] = qq;
    }
    __syncthreads();
    red[tid] = (tid < 100) ? sd_s[tid] : -3e38f; __syncthreads();
    for (int o = 128; o > 0; o >>= 1) { if (tid < o) red[tid] = fmaxf(red[tid], red[tid + o]); __syncthreads(); }
    float md = red[0]; __syncthreads();
    red[tid] = (tid < 100) ? expf(sd_s[tid] - md) : 0.f; __syncthreads();
    for (int o = 128; o > 0; o >>= 1) { if (tid < o) red[tid] += red[tid + o]; __syncthreads(); }
    float Sd = red[0]; __syncthreads();
    red[tid] = (tid < 100) ? sz_s[tid] : -3e38f; __syncthreads();
    for (int o = 128; o > 0; o >>= 1) { if (tid < o) red[tid] = fmaxf(red[tid], red[tid + o]); __syncthreads(); }
    float mz = red[0]; __syncthreads();
    red[tid] = (tid < 100) ? expf(sz_s[tid] - mz) : 0.f; __syncthreads();
    for (int o = 128; o > 0; o >>= 1) { if (tid < o) red[tid] += red[tid + o]; __syncthreads(); }
    float Sz = red[0]; __syncthreads();
    if (tid < 100) aL[tid] = (expf(sd_s[tid] - md) / Sd) * (expf(sz_s[tid] - mz) / Sz);
    __syncthreads();
    red[tid] = (tid < 100) ? aL[tid] : 0.f; __syncthreads();
    for (int o = 128; o > 0; o >>= 1) { if (tid < o) red[tid] += red[tid + o]; __syncthreads(); }
    float Sa = red[0]; __syncthreads();
    if (tid < 100) {
        float av = aL[tid] / (Sa + 1e-3f);
        aL[tid] = av;
        attn_ws[(size_t)m * 100 + tid] = av;
        AD[(size_t)m * 100 + tid] = av;
    }
    __syncthreads();
    red[tid] = (tid < 100) ? aL[tid] : -3e38f;
    ri[tid]  = (tid < 100) ? tid : 0x7fffffff;
    __syncthreads();
    for (int o = 128; o > 0; o >>= 1) {
        if (tid < o) {
            if (red[tid + o] > red[tid] || (red[tid + o] == red[tid] && ri[tid + o] < ri[tid])) {
                red[tid] = red[tid + o]; ri[tid] = ri[tid + o];
            }
        }
        __syncthreads();
    }
    if (tid == 0) widx[m] = value[b * 100 + ri[0]];
    if (tid < 64) {
        float p = (tid < 100) ? aL[tid] * E_wl[b * 100 + tid] : 0.f;
        if (tid + 64 < 100) p += aL[tid + 64] * E_wl[b * 100 + tid + 64];
        for (int off = 32; off > 0; off >>= 1) p += __shfl_down(p, off);
        if (tid == 0) AWL[m] = p;
    }
}

// outs[m][e] = tanh(hWo1 + a@E2 + b_out); lam[m] = sigmoid(hwl + awl + sxl + b_l)  (f32)
__global__ __launch_bounds__(256) void k_outs(const float* PROJ, const float* AD, const float* E2,
                                              const float* AWL, const float* SXL,
                                              const float* b_out, const float* b_l,
                                              float* outs32, float* lam_ws) {
    __shared__ float ad_s[100];
    int m = blockIdx.x, tid = threadIdx.x;
    int b = m / T, t = m - b * T;
    if (tid < 100) ad_s[tid] = AD[(size_t)m * 100 + tid];
    __syncthreads();
    const float* pr = PROJ + ((size_t)t * 32 + b) * OC;
#pragma unroll 2
    for (int e = tid; e < 512; e += 256) {
        if (e < 500) {
            float acc = pr[560 + e] + b_out[e];
            const float* e2 = E2 + (size_t)b * 50000 + e;
            for (int l = 0; l < 100; ++l) acc += ad_s[l] * e2[l * 500];
            outs32[(size_t)m * 512 + e] = tanhf(acc);
        } else {
            outs32[(size_t)m * 512 + e] = 0.f;
        }
    }
    if (tid == 0)
        lam_ws[m] = fsig(pr[1060] + AWL[m] + SXL[t * 32 + b] + b_l[0]);
}

__global__ void k_hTcT(float* out, const double* hdecF, const double* cdecF) {
    int i = blockIdx.x * 256 + threadIdx.x;
    if (i >= 16000) return;
    int b = i / 500, u = i - b * 500;
    out[OUT_HT + i] = (float)hdecF[u * 32 + b];
    out[OUT_CT + i] = (float)cdecF[u * 32 + b];
}

// ---------------- logits GEMM (f32, 128x128 tile, 8x8/thread): d_out = outs @ W_lin^T + b_lin ----

__global__ __launch_bounds__(256) void k_gemm_logits_f32(const float* outs32, const float* W_lin,
                                                         const float* b_lin, float* d_out) {
    __shared__ float As[16][132], Bs[16][132];
    int n0 = blockIdx.x * 128, m0 = blockIdx.y * 128;
    int tid = threadIdx.x;
    int ty = tid >> 4, tx = tid & 15;          // 16x16 threads, 8x8 each
    int lr = tid >> 1, lh = tid & 1;           // loader: row 0..127, k-half
    float acc[8][8];
#pragma unroll
    for (int i = 0; i < 8; ++i)
#pragma unroll
        for (int j = 0; j < 8; ++j) acc[i][j] = 0.f;

    for (int k0 = 0; k0 < 512; k0 += 16) {
        int k8 = k0 + lh * 8;
        float4 a0, a1;
        int mrow = m0 + lr;
        if (mrow < 1600) {
            a0 = *(const float4*)(outs32 + (size_t)mrow * 512 + k8);
            a1 = *(const float4*)(outs32 + (size_t)mrow * 512 + k8 + 4);
        } else {
            a0 = make_float4(0.f, 0.f, 0.f, 0.f); a1 = a0;
        }
        float4 b0 = make_float4(0.f, 0.f, 0.f, 0.f), b1 = b0;
        int nrow = n0 + lr;
        if (nrow < VS) {
            if (k8 < 500)     b0 = *(const float4*)(W_lin + (size_t)nrow * 500 + k8);
            if (k8 + 4 < 500) b1 = *(const float4*)(W_lin + (size_t)nrow * 500 + k8 + 4);
        }
        __syncthreads();
        As[lh * 8 + 0][lr] = a0.x; As[lh * 8 + 1][lr] = a0.y;
        As[lh * 8 + 2][lr] = a0.z; As[lh * 8 + 3][lr] = a0.w;
        As[lh * 8 + 4][lr] = a1.x; As[lh * 8 + 5][lr] = a1.y;
        As[lh * 8 + 6][lr] = a1.z; As[lh * 8 + 7][lr] = a1.w;
        Bs[lh * 8 + 0][lr] = b0.x; Bs[lh * 8 + 1][lr] = b0.y;
        Bs[lh * 8 + 2][lr] = b0.z; Bs[lh * 8 + 3][lr] = b0.w;
        Bs[lh * 8 + 4][lr] = b1.x; Bs[lh * 8 + 5][lr] = b1.y;
        Bs[lh * 8 + 6][lr] = b1.z; Bs[lh * 8 + 7][lr] = b1.w;
        __syncthreads();
#pragma unroll
        for (int kk = 0; kk < 16; ++kk) {
            float4 av0 = *(const float4*)&As[kk][ty * 8];
            float4 av1 = *(const float4*)&As[kk][ty * 8 + 4];
            float4 bv0 = *(const float4*)&Bs[kk][tx * 8];
            float4 bv1 = *(const float4*)&Bs[kk][tx * 8 + 4];
            float ar[8] = {av0.x, av0.y, av0.z, av0.w, av1.x, av1.y, av1.z, av1.w};
            float br[8] = {bv0.x, bv0.y, bv0.z, bv0.w, bv1.x, bv1.y, bv1.z, bv1.w};
#pragma unroll
            for (int i = 0; i < 8; ++i)
#pragma unroll
                for (int j = 0; j < 8; ++j) acc[i][j] += ar[i] * br[j];
        }
    }
#pragma unroll
    for (int j = 0; j < 8; ++j) {
        int n = n0 + tx * 8 + j;
        if (n < VS) {
            float bl = b_lin[n];
#pragma unroll
            for (int i = 0; i < 8; ++i) {
                int mm = m0 + ty * 8 + i;
                if (mm < 1600)
                    d_out[(size_t)mm * VS + n] = acc[i][j] + bl;
            }
        }
    }
}

// ---------------- softmax passes ----------------

__global__ void k_red1(const float* d_out, float* LS1) {
    int m = blockIdx.x, tid = threadIdx.x;
    const float* row = d_out + (size_t)m * VS;
    __shared__ float red[256];
    float lm = -3e38f;
    for (int v = tid; v < VS; v += 256) lm = fmaxf(lm, row[v]);
    red[tid] = lm; __syncthreads();
    for (int o = 128; o > 0; o >>= 1) { if (tid < o) red[tid] = fmaxf(red[tid], red[tid + o]); __syncthreads(); }
    float m1 = red[0]; __syncthreads();
    float ls = 0.f;
    for (int v = tid; v < VS; v += 256) ls += expf(row[v] - m1);
    red[tid] = ls; __syncthreads();
    for (int o = 128; o > 0; o >>= 1) { if (tid < o) red[tid] += red[tid + o]; __syncthreads(); }
    if (tid == 0) LS1[m] = m1 + logf(red[0]);
}

__global__ __launch_bounds__(256) void k_plexmix(float* d_out, const float* attn_ws, const float* align_prob,
                                                 const float* lam_ws, const float* LS1) {
    int b = blockIdx.y, v0 = blockIdx.x * 64, tid = threadIdx.x;
    __shared__ float attn_s[50 * 100];
    __shared__ float al[100 * 64];
    for (int i = tid; i < 5000; i += 256) attn_s[i] = attn_ws[(size_t)b * 5000 + i];
    for (int i = tid; i < 6400; i += 256) {
        int l = i >> 6, j = i & 63;
        int v = v0 + j;
        al[i] = (v < VS) ? align_prob[((size_t)b * 100 + l) * VS + v] : 0.f;
    }
    __syncthreads();
    for (int idx = tid; idx < 50 * 64; idx += 256) {
        int t = idx >> 6, j = idx & 63;
        int v = v0 + j;
        if (v < VS) {
            float acc = 0.f;
            for (int l = 0; l < 100; ++l) acc += attn_s[t * 100 + l] * al[l * 64 + j];
            int m = b * T + t;
            size_t p = (size_t)m * VS + v;
            float lamv = lam_ws[m];
            d_out[p] = lamv * acc + (1.f - lamv) * (d_out[p] - LS1[m]);
        }
    }
}

__global__ void k_final2(float* d_out, const float* E_target) {
    int m = blockIdx.x, tid = threadIdx.x;
    float* row = d_out + (size_t)m * VS;
    __shared__ float sm[256], ss[256], sbv[256];
    __shared__ int sbi[256];
    float rm = -3e38f, rs = 0.f, bv = -3e38f; int bi = 0;
    for (int v = tid; v < VS; v += 256) {
        float xv = row[v];
        if (xv > bv) { bv = xv; bi = v; }
        if (xv > rm) { rs = rs * expf(rm - xv) + 1.f; rm = xv; }
        else rs += expf(xv - rm);
    }
    sm[tid] = rm; ss[tid] = rs; sbv[tid] = bv; sbi[tid] = bi;
    __syncthreads();
    for (int o = 128; o > 0; o >>= 1) {
        if (tid < o) {
            float m1 = sm[tid], m2 = sm[tid + o];
            float M = fmaxf(m1, m2);
            ss[tid] = ss[tid] * expf(m1 - M) + ss[tid + o] * expf(m2 - M);
            sm[tid] = M;
            if (sbv[tid + o] > sbv[tid] || (sbv[tid + o] == sbv[tid] && sbi[tid + o] < sbi[tid])) {
                sbv[tid] = sbv[tid + o]; sbi[tid] = sbi[tid + o];
            }
        }
        __syncthreads();
    }
    float ls2 = sm[0] + logf(ss[0]);
    int amax = sbi[0];
    for (int v = tid; v < VS; v += 256) row[v] -= ls2;
    for (int j = tid; j < 300; j += 256)
        d_out[OUT_DP + (size_t)m * 300 + j] = E_target[(size_t)amax * 300 + j];
}

__global__ void k_attnpred2(const int* widx, const float* E_target, float* d_out) {
    int i = blockIdx.x * 256 + threadIdx.x;
    if (i >= 1600 * 300) return;
    int m = i / 300, j = i - m * 300;
    d_out[OUT_AP + i] = E_target[(size_t)widx[m] * 300 + j];
}

// ---------------- launch ----------------

extern "C" void kernel_launch(void* const* d_in, const int* in_sizes, int n_in,
                              void* d_out_v, int out_size, void* d_ws, size_t ws_size,
                              hipStream_t stream) {
    const float* align_prob = (const float*)d_in[1];
    const float* E_sent     = (const float*)d_in[2];
    const float* E_field    = (const float*)d_in[3];
    const float* E_ppos     = (const float*)d_in[4];
    const float* E_pneg     = (const float*)d_in[5];
    const float* E_target   = (const float*)d_in[6];
    const float* enc_Wih_f  = (const float*)d_in[7];
    const float* enc_Whh_f  = (const float*)d_in[8];
    const float* enc_b_f    = (const float*)d_in[9];
    const float* enc_Wih_b  = (const float*)d_in[10];
    const float* enc_Whh_b  = (const float*)d_in[11];
    const float* enc_b_b    = (const float*)d_in[12];
    const float* dec_Wih    = (const float*)d_in[13];
    const float* dec_Whh    = (const float*)d_in[14];
    const float* dec_b      = (const float*)d_in[15];
    const float* W_d        = (const float*)d_in[16];
    const float* W_z        = (const float*)d_in[17];
    const float* W_out      = (const float*)d_in[18];
    const float* b_out      = (const float*)d_in[19];
    const float* w_l        = (const float*)d_in[20];
    const float* b_l        = (const float*)d_in[21];
    const float* W_lin      = (const float*)d_in[22];
    const float* b_lin      = (const float*)d_in[23];
    const int* sent  = (const int*)d_in[24];
    const int* value = (const int*)d_in[25];
    const int* field = (const int*)d_in[26];
    const int* ppos  = (const int*)d_in[27];
    const int* pneg  = (const int*)d_in[28];

    char* ws = (char*)d_ws;
    float*  x      = (float*)(ws + O_X);
    float*  sx     = (float*)(ws + O_SX);
    float*  WihfT  = (float*)(ws + O_WIHFT);
    float*  WihbT  = (float*)(ws + O_WIHBT);
    float*  WdecT  = (float*)(ws + O_WDECT);
    float*  w4encT = (float*)(ws + O_W4ENC);
    float*  w4decT = (float*)(ws + O_W4DEC);
    float*  Wcat   = (float*)(ws + O_WCAT);
    double* xwF    = (double*)(ws + O_XWF);
    double* xwB    = (double*)(ws + O_XWB);
    double* xwD    = (double*)(ws + O_XWD);
    float*  eoB    = (float*)(ws + O_EOB);
    float*  E2     = (float*)(ws + O_E2);
    float*  PROJ   = (float*)(ws + O_PROJ);
    double* EHB    = (double*)(ws + O_EHB);
    double* DHB    = (double*)(ws + O_DHB);
    float*  Hd     = (float*)(ws + O_HD);
    double* h0dec  = (double*)(ws + O_H0DEC);
    double* hencF  = (double*)(ws + O_HENCF);
    double* cencF  = (double*)(ws + O_CENCF);
    double* cdec0  = (double*)(ws + O_CDEC0);
    double* hdecF  = (double*)(ws + O_HDECF);
    double* cdecF  = (double*)(ws + O_CDECF);
    float*  AD     = (float*)(ws + O_AD);
    float*  attn_ws= (float*)(ws + O_ATTN);
    float*  E_wl   = (float*)(ws + O_EWL);
    float*  SXL    = (float*)(ws + O_SXL);
    float*  AWL    = (float*)(ws + O_AWL);
    float*  lam_ws = (float*)(ws + O_LAM);
    float*  LS1    = (float*)(ws + O_LS1);
    int*    widx   = (int*)(ws + O_WIDX);
    float*  outs32 = (float*)(ws + O_OUTS);
    int*    FLGE   = (int*)(ws + O_FLG);
    int*    FLGD   = (int*)(ws + O_FLG) + 8192;
    float* out = (float*)d_out_v;

    // ---- prep (parallel) ----
    k_embed_x<<<(B * L * INE + 255) / 256, 256, 0, stream>>>(E_sent, E_field, E_ppos, E_pneg,
                                                             value, field, ppos, pneg, x);
    k_embed_sent<<<(T * B * 400 + 255) / 256, 256, 0, stream>>>(E_sent, sent, sx);
    k_transpose<<<(460 * 1000 + 255) / 256, 256, 0, stream>>>(WihfT, enc_Wih_f, 460, 1000);
    k_transpose<<<(460 * 1000 + 255) / 256, 256, 0, stream>>>(WihbT, enc_Wih_b, 460, 1000);
    k_transpose<<<(400 * 2000 + 255) / 256, 256, 0, stream>>>(WdecT, dec_Wih, 400, 2000);
    k_pack4T<<<(250 * 250 * 4 + 255) / 256, 256, 0, stream>>>(w4encT, enc_Whh_f, 250, 250);
    k_pack4T<<<(250 * 250 * 4 + 255) / 256, 256, 0, stream>>>(w4encT + 250000, enc_Whh_b, 250, 250);
    k_pack4T<<<(500 * 500 * 4 + 255) / 256, 256, 0, stream>>>(w4decT, dec_Whh, 500, 500);
    k_pack_wcat<<<(500 * OC + 255) / 256, 256, 0, stream>>>(Wcat, W_d, W_z, W_out, w_l);
    k_zeroi<<<(16384 + 255) / 256, 256, 0, stream>>>(FLGE, 16384);   // both flag arrays
    k_sxl<<<(1600 + 255) / 256, 256, 0, stream>>>(sx, w_l, SXL);
    {
        dim3 g1(100, 4); k_gemm_xw<<<g1, 256, 0, stream>>>(xwF, x, L * INE, INE, WihfT, enc_b_f, 460, 1000);
        dim3 g2(100, 4); k_gemm_xw<<<g2, 256, 0, stream>>>(xwB, x, L * INE, INE, WihbT, enc_b_b, 460, 1000);
        dim3 g3(50, 8);  k_gemm_xw<<<g3, 256, 0, stream>>>(xwD, sx, 400, B * 400, WdecT, dec_b, 400, 2000);
    }

    // ---- encoder: 256 blocks = 64 chains x 4 u-quarters, register W-cache ----
    k_enc_u<<<256, 1024, 0, stream>>>(xwF, xwB, w4encT, EHB, FLGE, eoB, hencF, cencF);
    k_scramble<<<63, 256, 0, stream>>>(h0dec, cdec0, hencF, cencF);
    {
        dim3 ge(2, 200); k_e2_tiled<<<ge, 256, 0, stream>>>(eoB, W_out, E2);
    }
    k_ewl<<<800, 256, 0, stream>>>(eoB, w_l, E_wl);

    // ---- decoder: 256 blocks = 32 chains x 8 u-eighths, partial register W-cache ----
    k_dec_u<<<256, 1024, 0, stream>>>(h0dec, cdec0, xwD, w4decT, DHB, FLGD, Hd, hdecF, cdecF);
    k_hTcT<<<63, 256, 0, stream>>>(out, hdecF, cdecF);

    // ---- attention: fully batched, f32 ----
    {
        dim3 gp(5, 100); k_proj_tiled<<<gp, 256, 0, stream>>>(Hd, Wcat, PROJ);
    }
    k_attn_all<<<1600, 256, 0, stream>>>(PROJ, eoB, x, E_wl, value, attn_ws, AD, AWL, widx);
    k_outs<<<1600, 256, 0, stream>>>(PROJ, AD, E2, AWL, SXL, b_out, b_l, outs32, lam_ws);

    // ---- output head ----
    {
        dim3 gg(157, 13);
        k_gemm_logits_f32<<<gg, 256, 0, stream>>>(outs32, W_lin, b_lin, out);
    }
    k_red1<<<1600, 256, 0, stream>>>(out, LS1);
    {
        dim3 gp2(313, 32);
        k_plexmix<<<gp2, 256, 0, stream>>>(out, attn_ws, align_prob, lam_ws, LS1);
    }
    k_final2<<<1600, 256, 0, stream>>>(out, E_target);
    k_attnpred2<<<(1600 * 300 + 255) / 256, 256, 0, stream>>>(widx, E_target, out);
}

// Round 19
// 3039.359 us; speedup vs baseline: 1.4285x; 1.4285x over previous
//
#include <hip/hip_runtime.h>

#define DI __device__ __forceinline__

constexpr int B = 32, L = 100, T = 50;
constexpr int VS = 20000;
constexpr int HR = 250, HD = 500;
constexpr int INE = 460;
constexpr int OC = 1072;   // padded Wcat columns: 500 hwd | 60 hz | 500 hWo1 | 1 hwl | pad

// ---- workspace byte offsets ----
constexpr size_t O_X      = 0;                      // x [B][L][460] f32
constexpr size_t O_SX     = 5888000;                // sent_x [T][B][400] f32
constexpr size_t O_WIHFT  = 8448000;                // enc_Wih_f^T [460][1000] f32
constexpr size_t O_WIHBT  = 10288000;
constexpr size_t O_WDECT  = 12128000;               // dec_Wih^T [400][2000] f32
constexpr size_t O_W4ENC  = 15328000;               // transposed [2dir][250k][250u][4g] f32
constexpr size_t O_W4DEC  = 17328000;               // transposed [500k][500u][4g] f32
constexpr size_t O_WCAT   = 21328000;               // [500][1072] f32
constexpr size_t O_XWF    = 23472000;               // [100][32b][1000] f64  (b-major)
constexpr size_t O_XWB    = 49072000;
constexpr size_t O_XWD    = 74672000;               // [50][32b][2000] f64
constexpr size_t O_EOB    = 100272000;              // enc_out [32][100][500] f32
constexpr size_t O_E2     = 113072000;              // [32][100][500] f32
constexpr size_t O_PROJ   = 125872000;              // [50][32][1072] f32 (written AFTER dec)
// recurrence h-exchange buffers overlay the (later-written) PROJ region:
constexpr size_t O_EHB    = O_PROJ;                 // enc h [64ch][256] f64
constexpr size_t O_DHB    = O_PROJ + 131072;        // dec h [32ch][512] f64
constexpr size_t O_HD     = 139593600;              // [1600][500] f32 (row t*32+b)
constexpr size_t O_H0DEC  = 146249600;              // [500][32] f64 scrambled h init
constexpr size_t O_HENCF  = 146505600;              // [2dir][250][32] f64 final
constexpr size_t O_CENCF  = 146633600;
constexpr size_t O_CDEC0  = 146761600;              // [500][32] f64 scrambled c init
constexpr size_t O_HDECF  = 146889600;              // [500][32] f64 final
constexpr size_t O_CDECF  = 147017600;
constexpr size_t O_AD     = 147145600;              // a f32 [1600][100]
constexpr size_t O_ATTN   = 148425600;              // [32][50][100] f32
constexpr size_t O_EWL    = 149065600;              // [32][100] f32
constexpr size_t O_SXL    = 149091200;              // [1600] f32 (t*32+b)
constexpr size_t O_AWL    = 149104000;              // [1600] f32 (b*50+t)
constexpr size_t O_LAM    = 149116800;              // [1600] f32
constexpr size_t O_LS1    = 149123200;              // [1600] f32
constexpr size_t O_WIDX   = 149129600;              // [1600] int
constexpr size_t O_OUTS   = 149144192;              // outs f32 [1600][512]
constexpr size_t O_FLG    = 154090496;              // enc flags 8192 int | dec flags 8192 int
// end ~154.2 MB (<=158.4MB proven)

// output element offsets (f32)
constexpr size_t OUT_HT  = 32000000;
constexpr size_t OUT_CT  = 32016000;
constexpr size_t OUT_AP  = 32032000;
constexpr size_t OUT_DP  = 32512000;

DI double dsig(double x) { return 1.0 / (1.0 + exp(-x)); }
DI float fsig(float x) { return 1.f / (1.f + expf(-x)); }

// coherent (cache-bypassing, agent-scope) ops — the cross-block data path
DI double cld(const double* p) {
    return __hip_atomic_load(p, __ATOMIC_RELAXED, __HIP_MEMORY_SCOPE_AGENT);
}
DI void cst(double* p, double v) {
    __hip_atomic_store(p, v, __ATOMIC_RELAXED, __HIP_MEMORY_SCOPE_AGENT);
}
DI int cldi(const int* p) {
    return __hip_atomic_load(p, __ATOMIC_RELAXED, __HIP_MEMORY_SCOPE_AGENT);
}
DI void csti(int* p, int v) {
    __hip_atomic_store(p, v, __ATOMIC_RELAXED, __HIP_MEMORY_SCOPE_AGENT);
}
DI void spinge(const int* p, int target) {
    int spins = 0;
    while (cldi(p) < target) {
        __builtin_amdgcn_s_sleep(1);
        if (++spins > 50000000) break;     // bounded: no hang on bug
    }
}

// ---------------- prep kernels ----------------

__global__ void k_embed_x(const float* Es, const float* Ef, const float* Ep, const float* En,
                          const int* value, const int* field, const int* ppos, const int* pneg,
                          float* x) {
    int i = blockIdx.x * 256 + threadIdx.x;
    if (i >= B * L * INE) return;
    int j = i % INE, bl = i / INE;
    float v;
    if (j < 400)      v = Es[(size_t)value[bl] * 400 + j];
    else if (j < 450) v = Ef[(size_t)field[bl] * 50 + (j - 400)];
    else if (j < 455) v = Ep[(size_t)ppos[bl] * 5 + (j - 450)];
    else              v = En[(size_t)pneg[bl] * 5 + (j - 455)];
    x[i] = v;
}

__global__ void k_embed_sent(const float* Es, const int* sent, float* sx) {
    int i = blockIdx.x * 256 + threadIdx.x;
    if (i >= T * B * 400) return;
    int k = i % 400, tb = i / 400;
    int b = tb % B, t = tb / B;
    sx[i] = Es[(size_t)sent[b * T + t] * 400 + k];
}

__global__ void k_transpose(float* dst, const float* src, int K, int G) {
    int i = blockIdx.x * 256 + threadIdx.x;
    if (i >= K * G) return;
    int g = i % G, k = i / G;
    dst[i] = src[(size_t)g * K + k];
}

// transposed gate-pack: dst[(k*U + u)*4 + g] = src[(g*U+u)*Kh + k]
__global__ void k_pack4T(float* dst, const float* src, int U, int Kh) {
    int i = blockIdx.x * 256 + threadIdx.x;
    if (i >= U * Kh * 4) return;
    int g = i & 3, rest = i >> 2;
    int u = rest % U, k = rest / U;
    dst[i] = src[((size_t)(g * U + u)) * Kh + k];
}

__global__ void k_pack_wcat(float* dst, const float* Wd, const float* Wz, const float* Wo, const float* wl) {
    int i = blockIdx.x * 256 + threadIdx.x;
    if (i >= 500 * OC) return;
    int o = i % OC, d = i / OC;
    float v = 0.f;
    if (o < 500)       v = Wd[(size_t)d * 500 + o];
    else if (o < 560)  v = Wz[(size_t)d * 60 + (o - 500)];
    else if (o < 1060) v = Wo[(size_t)d * 500 + (o - 560)];
    else if (o == 1060) v = wl[d];
    dst[i] = v;
}

__global__ void k_zeroi(int* p, int n) {
    int i = blockIdx.x * 256 + threadIdx.x;
    if (i < n) p[i] = 0;
}

// out[t][b][g] = bias[g] + sum_k xs[b,t,k] * Wt[k][g]   (f64 accumulate — feeds the chaotic chain)
__global__ __launch_bounds__(256) void k_gemm_xw(double* out, const float* xs, int bstride, int tstride,
                                                 const float* Wt, const float* bias, int K, int G) {
    __shared__ float xls[460 * 33];
    int t = blockIdx.x;
    int g = blockIdx.y * 256 + threadIdx.x;
    bool act = g < G;
    for (int i = threadIdx.x; i < 32 * K; i += 256) {
        int b = i / K, k = i - b * K;
        xls[k * 33 + b] = xs[(size_t)b * bstride + (size_t)t * tstride + k];
    }
    __syncthreads();
    double acc[32];
    double bs = act ? (double)bias[g] : 0.0;
#pragma unroll
    for (int b = 0; b < 32; ++b) acc[b] = bs;
    for (int k = 0; k < K; ++k) {
        double w = act ? (double)Wt[(size_t)k * G + g] : 0.0;
        const float* xr = &xls[k * 33];
#pragma unroll
        for (int b = 0; b < 32; ++b) acc[b] += w * (double)xr[b];
    }
    if (act) {
#pragma unroll
        for (int b = 0; b < 32; ++b)
            out[((size_t)t * 32 + b) * G + g] = acc[b];
    }
}

// ---------------- encoder: 256 blocks = 64 chains x 4 u-quarters, ONE exchange/step ----------------

__global__ __launch_bounds__(1024) void k_enc_u(const double* xw2F, const double* xw2B,
                                                const float* w4T, double* HB, int* FLG,
                                                float* eoB, double* hencF, double* cencF) {
    __shared__ double h_s[256];
    __shared__ double pz[15][4][64];          // kc 1..15 partials, [gate][ul] conflict-free
    int gid = blockIdx.x;
    int chain = gid >> 2, q = gid & 3;
    int dir = chain >> 5, b = chain & 31;
    int tid = threadIdx.x;
    int kc = tid >> 6, ul = tid & 63;
    int u0 = (q * 250) >> 2, u1 = ((q + 1) * 250) >> 2;
    int nu = u1 - u0;                          // 62 or 63
    int u = u0 + ul;
    bool act = ul < nu;
    int ks = (kc * 250) >> 4, ke = ((kc + 1) * 250) >> 4;
    const double* xw = dir ? xw2B : xw2F;
    const float4* W = (const float4*)w4T + (size_t)dir * 250 * 250;   // [k][u]
    double* myHB = HB + (size_t)chain * 256;
    int* flg = FLG + chain * 64;               // 4 slots x 16 ints
    double c = 0.0;
    if (tid < 256) h_s[tid] = 0.0;
    __syncthreads();
    for (int s = 0; s < L; ++s) {
        int tin = dir ? (L - 1 - s) : s;
        double zi = 0.0, zf = 0.0, zg = 0.0, zo = 0.0;
        if (act) {
#pragma unroll 4
            for (int k = ks; k < ke; ++k) {
                float4 w = W[(size_t)k * 250 + u];   // 1KB/wave/k, L2-resident
                double hv = h_s[k];
                zi += (double)w.x * hv; zf += (double)w.y * hv;
                zg += (double)w.z * hv; zo += (double)w.w * hv;
            }
            if (kc) { pz[kc - 1][0][ul] = zi; pz[kc - 1][1][ul] = zf;
                      pz[kc - 1][2][ul] = zg; pz[kc - 1][3][ul] = zo; }
        }
        __syncthreads();
        if (act && kc == 0) {
            const double* x0 = xw + ((size_t)tin * 32 + b) * 1000;
            double Zi = x0[0 * HR + u] + zi, Zf = x0[1 * HR + u] + zf;
            double Zg = x0[2 * HR + u] + zg, Zo = x0[3 * HR + u] + zo;
#pragma unroll
            for (int j = 0; j < 15; ++j) {
                Zi += pz[j][0][ul]; Zf += pz[j][1][ul];
                Zg += pz[j][2][ul]; Zo += pz[j][3][ul];
            }
            double cn = dsig(Zf) * c + dsig(Zi) * tanh(Zg);
            double hn = dsig(Zo) * tanh(cn);
            c = cn;
            cst(&myHB[u], hn);
            eoB[((size_t)b * 100 + tin) * 500 + dir * 250 + u] = (float)hn;
            if (s == L - 1) {
                hencF[dir * 8000 + u * 32 + b] = hn;
                cencF[dir * 8000 + u * 32 + b] = cn;
            }
        }
        __syncthreads();                      // drain coherent h stores (release)
        if (tid == 0) csti(&flg[q * 16], s + 1);
        if (tid < 4) spinge(&flg[tid * 16], s + 1);
        __syncthreads();
        if (tid < 250) h_s[tid] = cld(&myHB[tid]);
        __syncthreads();
    }
}

// replicate torch .view on [2,B,250] -> [B,500]
__global__ void k_scramble(double* h0dec, double* cdec0, const double* hencF, const double* cencF) {
    int gt = blockIdx.x * 256 + threadIdx.x;
    if (gt >= 16000) return;
    int bb = gt / 500, j = gt - bb * 500;
    int d = gt / 8000, rem = gt - d * 8000;
    int bs = rem / 250, us = rem - bs * 250;
    h0dec[j * 32 + bb] = hencF[d * 8000 + us * 32 + bs];
    cdec0[j * 32 + bb] = cencF[d * 8000 + us * 32 + bs];
}

// ---------------- decoder: 256 blocks = 32 chains x 8 u-eighths, ONE exchange/step ----------------

__global__ __launch_bounds__(1024) void k_dec_u(const double* h0dec, const double* cdec0,
                                                const double* xw2D, const float* w4T,
                                                double* HB, int* FLG,
                                                float* Hd, double* hdecF, double* cdecF) {
    __shared__ double h_s[512];
    __shared__ double pz[15][4][64];
    int gid = blockIdx.x;
    int chain = gid >> 3, q = gid & 7;
    int b = chain;
    int tid = threadIdx.x;
    int kc = tid >> 6, ul = tid & 63;
    int u0 = (q * 500) >> 3, u1 = ((q + 1) * 500) >> 3;
    int nu = u1 - u0;                          // 62 or 63
    int u = u0 + ul;
    bool act = ul < nu;
    int ks = (kc * 500) >> 4, ke = ((kc + 1) * 500) >> 4;
    const float4* W = (const float4*)w4T;      // [k][u]
    double* myHB = HB + (size_t)chain * 512;
    int* flg = FLG + chain * 128;              // 8 slots x 16 ints
    double c = (act && kc == 0) ? cdec0[u * 32 + b] : 0.0;
    if (tid < 512) h_s[tid] = (tid < 500) ? h0dec[tid * 32 + b] : 0.0;
    __syncthreads();
    for (int t = 0; t < T; ++t) {
        double zi = 0.0, zf = 0.0, zg = 0.0, zo = 0.0;
        if (act) {
#pragma unroll 4
            for (int k = ks; k < ke; ++k) {
                float4 w = W[(size_t)k * 500 + u];   // 1KB/wave/k, L2-resident
                double hv = h_s[k];
                zi += (double)w.x * hv; zf += (double)w.y * hv;
                zg += (double)w.z * hv; zo += (double)w.w * hv;
            }
            if (kc) { pz[kc - 1][0][ul] = zi; pz[kc - 1][1][ul] = zf;
                      pz[kc - 1][2][ul] = zg; pz[kc - 1][3][ul] = zo; }
        }
        __syncthreads();
        if (act && kc == 0) {
            const double* x0 = xw2D + ((size_t)t * 32 + b) * 2000;
            double Zi = x0[0 * HD + u] + zi, Zf = x0[1 * HD + u] + zf;
            double Zg = x0[2 * HD + u] + zg, Zo = x0[3 * HD + u] + zo;
#pragma unroll
            for (int j = 0; j < 15; ++j) {
                Zi += pz[j][0][ul]; Zf += pz[j][1][ul];
                Zg += pz[j][2][ul]; Zo += pz[j][3][ul];
            }
            double cn = dsig(Zf) * c + dsig(Zi) * tanh(Zg);
            double hn = dsig(Zo) * tanh(cn);
            c = cn;
            cst(&myHB[u], hn);
            Hd[((size_t)t * 32 + b) * 500 + u] = (float)hn;
            if (t == T - 1) {
                hdecF[u * 32 + b] = hn;
                cdecF[u * 32 + b] = cn;
            }
        }
        __syncthreads();                      // drain coherent h stores (release)
        if (tid == 0) csti(&flg[q * 16], t + 1);
        if (tid < 8) spinge(&flg[tid * 16], t + 1);
        __syncthreads();
        if (tid < 500) h_s[tid] = cld(&myHB[tid]);
        __syncthreads();
    }
}

// ---------------- attention precomputes (f32 — post-recurrence, bf16-graded outputs) ----------------

// E2[r][e] = sum_j eoB[r][j] * Wo[(500+j)][e] — 16-row tile x 256-col strip
__global__ __launch_bounds__(256) void k_e2_tiled(const float* eoB, const float* Wo, float* E2) {
    __shared__ float rows[8000];
    int et = blockIdx.x, mt = blockIdx.y;
    int tid = threadIdx.x;
    size_t rbase = (size_t)mt * 16 * 500;
    for (int i = tid; i < 8000; i += 256) rows[i] = eoB[rbase + i];
    __syncthreads();
    int e = et * 256 + tid;
    if (e >= 500) return;
    float acc[16];
#pragma unroll
    for (int m = 0; m < 16; ++m) acc[m] = 0.f;
    for (int d = 0; d < 500; ++d) {
        float w = Wo[(size_t)(500 + d) * 500 + e];
#pragma unroll
        for (int m = 0; m < 16; ++m) acc[m] += rows[m * 500 + d] * w;
    }
#pragma unroll
    for (int m = 0; m < 16; ++m) E2[rbase + (size_t)m * 500 + e] = acc[m];
}

__global__ void k_ewl(const float* eoB, const float* wl, float* E_wl) {
    int w = threadIdx.x >> 6, lane = threadIdx.x & 63;
    int r = blockIdx.x * 4 + w;
    if (r >= 3200) return;
    const float* eo = eoB + (size_t)r * 500;
    float p = 0.f;
    for (int j = lane; j < 500; j += 64) p += eo[j] * wl[500 + j];
    for (int off = 32; off > 0; off >>= 1) p += __shfl_down(p, off);
    if (lane == 0) E_wl[r] = p;
}

__global__ void k_sxl(const float* sx, const float* wl, float* SXL) {
    int i = blockIdx.x * 256 + threadIdx.x;
    if (i >= 1600) return;
    float acc = 0.f;
    for (int k = 0; k < 400; ++k) acc += sx[(size_t)i * 400 + k] * wl[1000 + k];
    SXL[i] = acc;
}

// PROJ[m2][o] = sum_d Hd[m2][d] * Wcat[d][o] — 16-row tile x 256-col strip
__global__ __launch_bounds__(256) void k_proj_tiled(const float* Hd, const float* Wcat, float* PROJ) {
    __shared__ float rows[8000];
    int ot = blockIdx.x, mt = blockIdx.y;
    int tid = threadIdx.x;
    size_t rbase = (size_t)mt * 16 * 500;
    for (int i = tid; i < 8000; i += 256) rows[i] = Hd[rbase + i];
    __syncthreads();
    int o = ot * 256 + tid;
    if (o >= OC) return;
    float acc[16];
#pragma unroll
    for (int m = 0; m < 16; ++m) acc[m] = 0.f;
    for (int d = 0; d < 500; ++d) {
        float w = Wcat[(size_t)d * OC + o];
#pragma unroll
        for (int m = 0; m < 16; ++m) acc[m] += rows[m * 500 + d] * w;
    }
#pragma unroll
    for (int m = 0; m < 16; ++m)
        PROJ[((size_t)(mt * 16 + m)) * OC + o] = acc[m];
}

// scores + dual softmax + attn/AD/widx/awl : one block per (t,b), f32
__global__ __launch_bounds__(256) void k_attn_all(
        const float* PROJ, const float* eoB, const float* x, const float* E_wl, const int* value,
        float* attn_ws, float* AD, float* AWL, int* widx) {
    int bid = blockIdx.x;              // = t*32+b
    int t = bid >> 5, b = bid & 31;
    int tid = threadIdx.x;
    int m = b * T + t;
    __shared__ float hwd_s[500], hz_s[60], sd_s[100], sz_s[100], aL[100];
    __shared__ float red[256];
    __shared__ int ri[256];
    const float* pr = PROJ + (size_t)bid * OC;
    for (int k = tid; k < 500; k += 256) hwd_s[k] = pr[k];
    if (tid < 60) hz_s[tid] = pr[500 + tid];
    __syncthreads();
    int w = tid >> 6, lane = tid & 63;
    for (int l = w; l < 100; l += 4) {
        const float* er = eoB + ((size_t)b * 100 + l) * 500;
        float p = 0.f;
        for (int e = lane; e < 500; e += 64) p += hwd_s[e] * er[e];
        for (int off = 32; off > 0; off >>= 1) p += __shfl_down(p, off);
        if (lane == 0) sd_s[l] = p;
        const float* zr = x + ((size_t)b * 100 + l) * 460 + 400;
        float qq = (lane < 60) ? hz_s[lane] * zr[lane] : 0.f;
        for (int off = 32; off > 0; off >>= 1) qq += __shfl_down(qq, off);
        if (lane == 0) sz_s[l] = qq;
    }
    __syncthreads();
    red[tid] = (tid < 100) ? sd_s[tid] : -3e38f; __syncthreads();
    for (int o = 128; o > 0; o >>= 1) { if (tid < o) red[tid] = fmaxf(red[tid], red[tid + o]); __syncthreads(); }
    float md = red[0]; __syncthreads();
    red[tid] = (tid < 100) ? expf(sd_s[tid] - md) : 0.f; __syncthreads();
    for (int o = 128; o > 0; o >>= 1) { if (tid < o) red[tid] += red[tid + o]; __syncthreads(); }
    float Sd = red[0]; __syncthreads();
    red[tid] = (tid < 100) ? sz_s[tid] : -3e38f; __syncthreads();
    for (int o = 128; o > 0; o >>= 1) { if (tid < o) red[tid] = fmaxf(red[tid], red[tid + o]); __syncthreads(); }
    float mz = red[0]; __syncthreads();
    red[tid] = (tid < 100) ? expf(sz_s[tid] - mz) : 0.f; __syncthreads();
    for (int o = 128; o > 0; o >>= 1) { if (tid < o) red[tid] += red[tid + o]; __syncthreads(); }
    float Sz = red[0]; __syncthreads();
    if (tid < 100) aL[tid] = (expf(sd_s[tid] - md) / Sd) * (expf(sz_s[tid] - mz) / Sz);
    __syncthreads();
    red[tid] = (tid < 100) ? aL[tid] : 0.f; __syncthreads();
    for (int o = 128; o > 0; o >>= 1) { if (tid < o) red[tid] += red[tid + o]; __syncthreads(); }
    float Sa = red[0]; __syncthreads();
    if (tid < 100) {
        float av = aL[tid] / (Sa + 1e-3f);
        aL[tid] = av;
        attn_ws[(size_t)m * 100 + tid] = av;
        AD[(size_t)m * 100 + tid] = av;
    }
    __syncthreads();
    red[tid] = (tid < 100) ? aL[tid] : -3e38f;
    ri[tid]  = (tid < 100) ? tid : 0x7fffffff;
    __syncthreads();
    for (int o = 128; o > 0; o >>= 1) {
        if (tid < o) {
            if (red[tid + o] > red[tid] || (red[tid + o] == red[tid] && ri[tid + o] < ri[tid])) {
                red[tid] = red[tid + o]; ri[tid] = ri[tid + o];
            }
        }
        __syncthreads();
    }
    if (tid == 0) widx[m] = value[b * 100 + ri[0]];
    if (tid < 64) {
        float p = (tid < 100) ? aL[tid] * E_wl[b * 100 + tid] : 0.f;
        if (tid + 64 < 100) p += aL[tid + 64] * E_wl[b * 100 + tid + 64];
        for (int off = 32; off > 0; off >>= 1) p += __shfl_down(p, off);
        if (tid == 0) AWL[m] = p;
    }
}

// outs[m][e] = tanh(hWo1 + a@E2 + b_out); lam[m] = sigmoid(hwl + awl + sxl + b_l)  (f32)
__global__ __launch_bounds__(256) void k_outs(const float* PROJ, const float* AD, const float* E2,
                                              const float* AWL, const float* SXL,
                                              const float* b_out, const float* b_l,
                                              float* outs32, float* lam_ws) {
    __shared__ float ad_s[100];
    int m = blockIdx.x, tid = threadIdx.x;
    int b = m / T, t = m - b * T;
    if (tid < 100) ad_s[tid] = AD[(size_t)m * 100 + tid];
    __syncthreads();
    const float* pr = PROJ + ((size_t)t * 32 + b) * OC;
#pragma unroll 2
    for (int e = tid; e < 512; e += 256) {
        if (e < 500) {
            float acc = pr[560 + e] + b_out[e];
            const float* e2 = E2 + (size_t)b * 50000 + e;
            for (int l = 0; l < 100; ++l) acc += ad_s[l] * e2[l * 500];
            outs32[(size_t)m * 512 + e] = tanhf(acc);
        } else {
            outs32[(size_t)m * 512 + e] = 0.f;
        }
    }
    if (tid == 0)
        lam_ws[m] = fsig(pr[1060] + AWL[m] + SXL[t * 32 + b] + b_l[0]);
}

__global__ void k_hTcT(float* out, const double* hdecF, const double* cdecF) {
    int i = blockIdx.x * 256 + threadIdx.x;
    if (i >= 16000) return;
    int b = i / 500, u = i - b * 500;
    out[OUT_HT + i] = (float)hdecF[u * 32 + b];
    out[OUT_CT + i] = (float)cdecF[u * 32 + b];
}

// ---------------- logits GEMM (f32, 128x128 tile, 8x8/thread): d_out = outs @ W_lin^T + b_lin ----

__global__ __launch_bounds__(256) void k_gemm_logits_f32(const float* outs32, const float* W_lin,
                                                         const float* b_lin, float* d_out) {
    __shared__ float As[16][132], Bs[16][132];
    int n0 = blockIdx.x * 128, m0 = blockIdx.y * 128;
    int tid = threadIdx.x;
    int ty = tid >> 4, tx = tid & 15;          // 16x16 threads, 8x8 each
    int lr = tid >> 1, lh = tid & 1;           // loader: row 0..127, k-half
    float acc[8][8];
#pragma unroll
    for (int i = 0; i < 8; ++i)
#pragma unroll
        for (int j = 0; j < 8; ++j) acc[i][j] = 0.f;

    for (int k0 = 0; k0 < 512; k0 += 16) {
        int k8 = k0 + lh * 8;
        float4 a0, a1;
        int mrow = m0 + lr;
        if (mrow < 1600) {
            a0 = *(const float4*)(outs32 + (size_t)mrow * 512 + k8);
            a1 = *(const float4*)(outs32 + (size_t)mrow * 512 + k8 + 4);
        } else {
            a0 = make_float4(0.f, 0.f, 0.f, 0.f); a1 = a0;
        }
        float4 b0 = make_float4(0.f, 0.f, 0.f, 0.f), b1 = b0;
        int nrow = n0 + lr;
        if (nrow < VS) {
            if (k8 < 500)     b0 = *(const float4*)(W_lin + (size_t)nrow * 500 + k8);
            if (k8 + 4 < 500) b1 = *(const float4*)(W_lin + (size_t)nrow * 500 + k8 + 4);
        }
        __syncthreads();
        As[lh * 8 + 0][lr] = a0.x; As[lh * 8 + 1][lr] = a0.y;
        As[lh * 8 + 2][lr] = a0.z; As[lh * 8 + 3][lr] = a0.w;
        As[lh * 8 + 4][lr] = a1.x; As[lh * 8 + 5][lr] = a1.y;
        As[lh * 8 + 6][lr] = a1.z; As[lh * 8 + 7][lr] = a1.w;
        Bs[lh * 8 + 0][lr] = b0.x; Bs[lh * 8 + 1][lr] = b0.y;
        Bs[lh * 8 + 2][lr] = b0.z; Bs[lh * 8 + 3][lr] = b0.w;
        Bs[lh * 8 + 4][lr] = b1.x; Bs[lh * 8 + 5][lr] = b1.y;
        Bs[lh * 8 + 6][lr] = b1.z; Bs[lh * 8 + 7][lr] = b1.w;
        __syncthreads();
#pragma unroll
        for (int kk = 0; kk < 16; ++kk) {
            float4 av0 = *(const float4*)&As[kk][ty * 8];
            float4 av1 = *(const float4*)&As[kk][ty * 8 + 4];
            float4 bv0 = *(const float4*)&Bs[kk][tx * 8];
            float4 bv1 = *(const float4*)&Bs[kk][tx * 8 + 4];
            float ar[8] = {av0.x, av0.y, av0.z, av0.w, av1.x, av1.y, av1.z, av1.w};
            float br[8] = {bv0.x, bv0.y, bv0.z, bv0.w, bv1.x, bv1.y, bv1.z, bv1.w};
#pragma unroll
            for (int i = 0; i < 8; ++i)
#pragma unroll
                for (int j = 0; j < 8; ++j) acc[i][j] += ar[i] * br[j];
        }
    }
#pragma unroll
    for (int j = 0; j < 8; ++j) {
        int n = n0 + tx * 8 + j;
        if (n < VS) {
            float bl = b_lin[n];
#pragma unroll
            for (int i = 0; i < 8; ++i) {
                int mm = m0 + ty * 8 + i;
                if (mm < 1600)
                    d_out[(size_t)mm * VS + n] = acc[i][j] + bl;
            }
        }
    }
}

// ---------------- softmax passes ----------------

__global__ void k_red1(const float* d_out, float* LS1) {
    int m = blockIdx.x, tid = threadIdx.x;
    const float* row = d_out + (size_t)m * VS;
    __shared__ float red[256];
    float lm = -3e38f;
    for (int v = tid; v < VS; v += 256) lm = fmaxf(lm, row[v]);
    red[tid] = lm; __syncthreads();
    for (int o = 128; o > 0; o >>= 1) { if (tid < o) red[tid] = fmaxf(red[tid], red[tid + o]); __syncthreads(); }
    float m1 = red[0]; __syncthreads();
    float ls = 0.f;
    for (int v = tid; v < VS; v += 256) ls += expf(row[v] - m1);
    red[tid] = ls; __syncthreads();
    for (int o = 128; o > 0; o >>= 1) { if (tid < o) red[tid] += red[tid + o]; __syncthreads(); }
    if (tid == 0) LS1[m] = m1 + logf(red[0]);
}

__global__ __launch_bounds__(256) void k_plexmix(float* d_out, const float* attn_ws, const float* align_prob,
                                                 const float* lam_ws, const float* LS1) {
    int b = blockIdx.y, v0 = blockIdx.x * 64, tid = threadIdx.x;
    __shared__ float attn_s[50 * 100];
    __shared__ float al[100 * 64];
    for (int i = tid; i < 5000; i += 256) attn_s[i] = attn_ws[(size_t)b * 5000 + i];
    for (int i = tid; i < 6400; i += 256) {
        int l = i >> 6, j = i & 63;
        int v = v0 + j;
        al[i] = (v < VS) ? align_prob[((size_t)b * 100 + l) * VS + v] : 0.f;
    }
    __syncthreads();
    for (int idx = tid; idx < 50 * 64; idx += 256) {
        int t = idx >> 6, j = idx & 63;
        int v = v0 + j;
        if (v < VS) {
            float acc = 0.f;
            for (int l = 0; l < 100; ++l) acc += attn_s[t * 100 + l] * al[l * 64 + j];
            int m = b * T + t;
            size_t p = (size_t)m * VS + v;
            float lamv = lam_ws[m];
            d_out[p] = lamv * acc + (1.f - lamv) * (d_out[p] - LS1[m]);
        }
    }
}

__global__ void k_final2(float* d_out, const float* E_target) {
    int m = blockIdx.x, tid = threadIdx.x;
    float* row = d_out + (size_t)m * VS;
    __shared__ float sm[256], ss[256], sbv[256];
    __shared__ int sbi[256];
    float rm = -3e38f, rs = 0.f, bv = -3e38f; int bi = 0;
    for (int v = tid; v < VS; v += 256) {
        float xv = row[v];
        if (xv > bv) { bv = xv; bi = v; }
        if (xv > rm) { rs = rs * expf(rm - xv) + 1.f; rm = xv; }
        else rs += expf(xv - rm);
    }
    sm[tid] = rm; ss[tid] = rs; sbv[tid] = bv; sbi[tid] = bi;
    __syncthreads();
    for (int o = 128; o > 0; o >>= 1) {
        if (tid < o) {
            float m1 = sm[tid], m2 = sm[tid + o];
            float M = fmaxf(m1, m2);
            ss[tid] = ss[tid] * expf(m1 - M) + ss[tid + o] * expf(m2 - M);
            sm[tid] = M;
            if (sbv[tid + o] > sbv[tid] || (sbv[tid + o] == sbv[tid] && sbi[tid + o] < sbi[tid])) {
                sbv[tid] = sbv[tid + o]; sbi[tid] = sbi[tid + o];
            }
        }
        __syncthreads();
    }
    float ls2 = sm[0] + logf(ss[0]);
    int amax = sbi[0];
    for (int v = tid; v < VS; v += 256) row[v] -= ls2;
    for (int j = tid; j < 300; j += 256)
        d_out[OUT_DP + (size_t)m * 300 + j] = E_target[(size_t)amax * 300 + j];
}

__global__ void k_attnpred2(const int* widx, const float* E_target, float* d_out) {
    int i = blockIdx.x * 256 + threadIdx.x;
    if (i >= 1600 * 300) return;
    int m = i / 300, j = i - m * 300;
    d_out[OUT_AP + i] = E_target[(size_t)widx[m] * 300 + j];
}

// ---------------- launch ----------------

extern "C" void kernel_launch(void* const* d_in, const int* in_sizes, int n_in,
                              void* d_out_v, int out_size, void* d_ws, size_t ws_size,
                              hipStream_t stream) {
    const float* align_prob = (const float*)d_in[1];
    const float* E_sent     = (const float*)d_in[2];
    const float* E_field    = (const float*)d_in[3];
    const float* E_ppos     = (const float*)d_in[4];
    const float* E_pneg     = (const float*)d_in[5];
    const float* E_target   = (const float*)d_in[6];
    const float* enc_Wih_f  = (const float*)d_in[7];
    const float* enc_Whh_f  = (const float*)d_in[8];
    const float* enc_b_f    = (const float*)d_in[9];
    const float* enc_Wih_b  = (const float*)d_in[10];
    const float* enc_Whh_b  = (const float*)d_in[11];
    const float* enc_b_b    = (const float*)d_in[12];
    const float* dec_Wih    = (const float*)d_in[13];
    const float* dec_Whh    = (const float*)d_in[14];
    const float* dec_b      = (const float*)d_in[15];
    const float* W_d        = (const float*)d_in[16];
    const float* W_z        = (const float*)d_in[17];
    const float* W_out      = (const float*)d_in[18];
    const float* b_out      = (const float*)d_in[19];
    const float* w_l        = (const float*)d_in[20];
    const float* b_l        = (const float*)d_in[21];
    const float* W_lin      = (const float*)d_in[22];
    const float* b_lin      = (const float*)d_in[23];
    const int* sent  = (const int*)d_in[24];
    const int* value = (const int*)d_in[25];
    const int* field = (const int*)d_in[26];
    const int* ppos  = (const int*)d_in[27];
    const int* pneg  = (const int*)d_in[28];

    char* ws = (char*)d_ws;
    float*  x      = (float*)(ws + O_X);
    float*  sx     = (float*)(ws + O_SX);
    float*  WihfT  = (float*)(ws + O_WIHFT);
    float*  WihbT  = (float*)(ws + O_WIHBT);
    float*  WdecT  = (float*)(ws + O_WDECT);
    float*  w4encT = (float*)(ws + O_W4ENC);
    float*  w4decT = (float*)(ws + O_W4DEC);
    float*  Wcat   = (float*)(ws + O_WCAT);
    double* xwF    = (double*)(ws + O_XWF);
    double* xwB    = (double*)(ws + O_XWB);
    double* xwD    = (double*)(ws + O_XWD);
    float*  eoB    = (float*)(ws + O_EOB);
    float*  E2     = (float*)(ws + O_E2);
    float*  PROJ   = (float*)(ws + O_PROJ);
    double* EHB    = (double*)(ws + O_EHB);
    double* DHB    = (double*)(ws + O_DHB);
    float*  Hd     = (float*)(ws + O_HD);
    double* h0dec  = (double*)(ws + O_H0DEC);
    double* hencF  = (double*)(ws + O_HENCF);
    double* cencF  = (double*)(ws + O_CENCF);
    double* cdec0  = (double*)(ws + O_CDEC0);
    double* hdecF  = (double*)(ws + O_HDECF);
    double* cdecF  = (double*)(ws + O_CDECF);
    float*  AD     = (float*)(ws + O_AD);
    float*  attn_ws= (float*)(ws + O_ATTN);
    float*  E_wl   = (float*)(ws + O_EWL);
    float*  SXL    = (float*)(ws + O_SXL);
    float*  AWL    = (float*)(ws + O_AWL);
    float*  lam_ws = (float*)(ws + O_LAM);
    float*  LS1    = (float*)(ws + O_LS1);
    int*    widx   = (int*)(ws + O_WIDX);
    float*  outs32 = (float*)(ws + O_OUTS);
    int*    FLGE   = (int*)(ws + O_FLG);
    int*    FLGD   = (int*)(ws + O_FLG) + 8192;
    float* out = (float*)d_out_v;

    // ---- prep (parallel) ----
    k_embed_x<<<(B * L * INE + 255) / 256, 256, 0, stream>>>(E_sent, E_field, E_ppos, E_pneg,
                                                             value, field, ppos, pneg, x);
    k_embed_sent<<<(T * B * 400 + 255) / 256, 256, 0, stream>>>(E_sent, sent, sx);
    k_transpose<<<(460 * 1000 + 255) / 256, 256, 0, stream>>>(WihfT, enc_Wih_f, 460, 1000);
    k_transpose<<<(460 * 1000 + 255) / 256, 256, 0, stream>>>(WihbT, enc_Wih_b, 460, 1000);
    k_transpose<<<(400 * 2000 + 255) / 256, 256, 0, stream>>>(WdecT, dec_Wih, 400, 2000);
    k_pack4T<<<(250 * 250 * 4 + 255) / 256, 256, 0, stream>>>(w4encT, enc_Whh_f, 250, 250);
    k_pack4T<<<(250 * 250 * 4 + 255) / 256, 256, 0, stream>>>(w4encT + 250000, enc_Whh_b, 250, 250);
    k_pack4T<<<(500 * 500 * 4 + 255) / 256, 256, 0, stream>>>(w4decT, dec_Whh, 500, 500);
    k_pack_wcat<<<(500 * OC + 255) / 256, 256, 0, stream>>>(Wcat, W_d, W_z, W_out, w_l);
    k_zeroi<<<(16384 + 255) / 256, 256, 0, stream>>>(FLGE, 16384);   // both flag arrays
    k_sxl<<<(1600 + 255) / 256, 256, 0, stream>>>(sx, w_l, SXL);
    {
        dim3 g1(100, 4); k_gemm_xw<<<g1, 256, 0, stream>>>(xwF, x, L * INE, INE, WihfT, enc_b_f, 460, 1000);
        dim3 g2(100, 4); k_gemm_xw<<<g2, 256, 0, stream>>>(xwB, x, L * INE, INE, WihbT, enc_b_b, 460, 1000);
        dim3 g3(50, 8);  k_gemm_xw<<<g3, 256, 0, stream>>>(xwD, sx, 400, B * 400, WdecT, dec_b, 400, 2000);
    }

    // ---- encoder: 256 blocks = 64 chains x 4 u-quarters, one exchange per step ----
    k_enc_u<<<256, 1024, 0, stream>>>(xwF, xwB, w4encT, EHB, FLGE, eoB, hencF, cencF);
    k_scramble<<<63, 256, 0, stream>>>(h0dec, cdec0, hencF, cencF);
    {
        dim3 ge(2, 200); k_e2_tiled<<<ge, 256, 0, stream>>>(eoB, W_out, E2);
    }
    k_ewl<<<800, 256, 0, stream>>>(eoB, w_l, E_wl);

    // ---- decoder: 256 blocks = 32 chains x 8 u-eighths ----
    k_dec_u<<<256, 1024, 0, stream>>>(h0dec, cdec0, xwD, w4decT, DHB, FLGD, Hd, hdecF, cdecF);
    k_hTcT<<<63, 256, 0, stream>>>(out, hdecF, cdecF);

    // ---- attention: fully batched, f32 ----
    {
        dim3 gp(5, 100); k_proj_tiled<<<gp, 256, 0, stream>>>(Hd, Wcat, PROJ);
    }
    k_attn_all<<<1600, 256, 0, stream>>>(PROJ, eoB, x, E_wl, value, attn_ws, AD, AWL, widx);
    k_outs<<<1600, 256, 0, stream>>>(PROJ, AD, E2, AWL, SXL, b_out, b_l, outs32, lam_ws);

    // ---- output head ----
    {
        dim3 gg(157, 13);
        k_gemm_logits_f32<<<gg, 256, 0, stream>>>(outs32, W_lin, b_lin, out);
    }
    k_red1<<<1600, 256, 0, stream>>>(out, LS1);
    {
        dim3 gp2(313, 32);
        k_plexmix<<<gp2, 256, 0, stream>>>(out, attn_ws, align_prob, lam_ws, LS1);
    }
    k_final2<<<1600, 256, 0, stream>>>(out, E_target);
    k_attnpred2<<<(1600 * 300 + 255) / 256, 256, 0, stream>>>(widx, E_target, out);
}